// Round 1
// baseline (204.968 us; speedup 1.0000x reference)
//
#include <hip/hip_runtime.h>
#include <stdint.h>

typedef unsigned short u16;
typedef __bf16 bfx8 __attribute__((ext_vector_type(8)));
typedef float f32x4 __attribute__((ext_vector_type(4)));

__device__ __forceinline__ u16 f2bf(float x) {
    unsigned int u = __float_as_uint(x);
    u += 0x7fffu + ((u >> 16) & 1u);
    return (u16)(u >> 16);
}

// async global->LDS 16B copy (dest must be linear: wave-uniform base + lane*16)
__device__ __forceinline__ void async16(const void* g, void* l) {
    __builtin_amdgcn_global_load_lds(
        (const __attribute__((address_space(1))) unsigned int*)(uintptr_t)g,
        (__attribute__((address_space(3))) unsigned int*)(unsigned int)(uintptr_t)l,
        16, 0, 0);
}

// ---------------------------------------------------------------------------
// elementwise f32 -> bf16 cast, 8 elems/thread
// ---------------------------------------------------------------------------
__global__ __launch_bounds__(256) void cast_bf16(const float* __restrict__ in,
                                                 u16* __restrict__ out, int n8) {
    int i = blockIdx.x * 256 + threadIdx.x;
    if (i >= n8) return;
    const float4* p = (const float4*)(in + (size_t)i * 8);
    float4 a = p[0], b = p[1];
    ushort4 o0, o1;
    o0.x = f2bf(a.x); o0.y = f2bf(a.y); o0.z = f2bf(a.z); o0.w = f2bf(a.w);
    o1.x = f2bf(b.x); o1.y = f2bf(b.y); o1.z = f2bf(b.z); o1.w = f2bf(b.w);
    ushort4* q = (ushort4*)(out + (size_t)i * 8);
    q[0] = o0; q[1] = o1;
}

// ---------------------------------------------------------------------------
// NT GEMM: C[M,N] = A[M,K] * Bw[N,K]^T   (A,Bw bf16 row-major)
// EPI 0: outb = bf16(C)
// EPI 1: outf = res + C                  (f32)
// EPI 2: outb = bf16(gelu(C + bias))     (exact gelu)
// EPI 3: outf = res + C + bias           (f32)
// 128x128 tile, BK=64, 4 waves (2x2), 4x4 16x16 frags/wave.
// LDS XOR swizzle: 16B chunk index ko stored at phys = ko ^ (row&7),
// applied on global source at stage time and on ds_read side.
// ---------------------------------------------------------------------------
template <int EPI>
__global__ __launch_bounds__(256, 2)
void gemm_nt(const u16* __restrict__ A, const u16* __restrict__ Bw,
             u16* __restrict__ outb, float* __restrict__ outf,
             const float* __restrict__ res, const float* __restrict__ bias,
             int M, int N, int K) {
    __shared__ __align__(1024) unsigned char lds[32768];
    unsigned char* ldsA = lds;
    unsigned char* ldsB = lds + 16384;
    const int t = threadIdx.x;
    const int lane = t & 63, w = t >> 6;
    const int laneR = lane & 15, laneK = lane >> 4;
    const int wr = w >> 1, wc = w & 1;
    const int row0 = blockIdx.y * 128, col0 = blockIdx.x * 128;

    f32x4 acc[4][4] = {};

    int sr[4], sko[4];
#pragma unroll
    for (int c = 0; c < 4; ++c) {
        int li = c * 256 + t;          // 16B-chunk linear index (1024 chunks/tile)
        sr[c] = li >> 3;               // row (128 rows x 8 chunks)
        sko[c] = (li & 7) ^ (sr[c] & 7);  // pre-swizzled source chunk
    }

    for (int kt = 0; kt < K; kt += 64) {
#pragma unroll
        for (int c = 0; c < 4; ++c) {
            int li = c * 256 + t;
            async16(A + (size_t)(row0 + sr[c]) * K + kt + sko[c] * 8, ldsA + li * 16);
            async16(Bw + (size_t)(col0 + sr[c]) * K + kt + sko[c] * 8, ldsB + li * 16);
        }
        __syncthreads();   // drains vmcnt -> staged data visible
#pragma unroll
        for (int ks = 0; ks < 2; ++ks) {
            bfx8 af[4], bfv[4];
#pragma unroll
            for (int m = 0; m < 4; ++m) {
                int r = wr * 64 + m * 16 + laneR;
                int phys = (ks * 4 + laneK) ^ (r & 7);
                af[m] = *(const bfx8*)(ldsA + r * 128 + phys * 16);
            }
#pragma unroll
            for (int n = 0; n < 4; ++n) {
                int r = wc * 64 + n * 16 + laneR;
                int phys = (ks * 4 + laneK) ^ (r & 7);
                bfv[n] = *(const bfx8*)(ldsB + r * 128 + phys * 16);
            }
#pragma unroll
            for (int m = 0; m < 4; ++m)
#pragma unroll
                for (int n = 0; n < 4; ++n)
                    acc[m][n] = __builtin_amdgcn_mfma_f32_16x16x32_bf16(
                        af[m], bfv[n], acc[m][n], 0, 0, 0);
        }
        __syncthreads();
    }

    // epilogue: D reg r of lane l -> row (l>>4)*4+r, col l&15 (per 16x16 frag)
#pragma unroll
    for (int m = 0; m < 4; ++m) {
#pragma unroll
        for (int n = 0; n < 4; ++n) {
            int gc = col0 + wc * 64 + n * 16 + laneR;
#pragma unroll
            for (int r = 0; r < 4; ++r) {
                int gr = row0 + wr * 64 + m * 16 + laneK * 4 + r;
                size_t idx = (size_t)gr * N + gc;
                float v = acc[m][n][r];
                if constexpr (EPI == 0) {
                    outb[idx] = f2bf(v);
                } else if constexpr (EPI == 1) {
                    outf[idx] = res[idx] + v;
                } else if constexpr (EPI == 2) {
                    float xx = v + bias[gc];
                    outb[idx] = f2bf(xx * 0.5f * (1.0f + erff(xx * 0.70710678118654752f)));
                } else {
                    outf[idx] = res[idx] + v + bias[gc];
                }
            }
        }
    }
}

// ---------------------------------------------------------------------------
// banded attention: WINDOW=32, 32-query tiles, 64-key band [i0-32, i0+31]
// scores via MFMA (per-wave H-chunk partials -> LDS reduce), masked softmax,
// PV via MFMA (P from LDS, V fragments gathered scalar from global).
// ---------------------------------------------------------------------------
__global__ __launch_bounds__(256, 2)
void attn_kernel(const u16* __restrict__ Q, const u16* __restrict__ K,
                 const u16* __restrict__ V, u16* __restrict__ O) {
    constexpr int H = 1024, S = 4096;
    const int t = threadIdx.x, lane = t & 63, w = t >> 6;
    const int laneR = lane & 15, laneK = lane >> 4;
    const int tile = blockIdx.x;      // 0..255
    const int batch = tile >> 7;
    const int i0 = (tile & 127) * 32; // within-batch first query row
    const size_t base = (size_t)batch * S * H;

    __shared__ __align__(16) float S4[4][32][64];
    __shared__ __align__(16) u16 P[32][72];  // padded rows (144B = 9*16B)

    // --- QK^T: wave w accumulates over H-chunk [w*256, w*256+256) ---
    f32x4 sc[2][4] = {};
    for (int h = w * 256; h < w * 256 + 256; h += 32) {
        bfx8 qa[2];
#pragma unroll
        for (int m = 0; m < 2; ++m) {
            size_t row = (size_t)(i0 + m * 16 + laneR);
            qa[m] = *(const bfx8*)(Q + base + row * H + h + laneK * 8);
        }
        bfx8 kb[4];
#pragma unroll
        for (int n = 0; n < 4; ++n) {
            int j = i0 - 32 + n * 16 + laneR;
            int jc = j < 0 ? 0 : j;            // clamped; masked later
            kb[n] = *(const bfx8*)(K + base + (size_t)jc * H + h + laneK * 8);
        }
#pragma unroll
        for (int m = 0; m < 2; ++m)
#pragma unroll
            for (int n = 0; n < 4; ++n)
                sc[m][n] = __builtin_amdgcn_mfma_f32_16x16x32_bf16(
                    qa[m], kb[n], sc[m][n], 0, 0, 0);
    }
#pragma unroll
    for (int m = 0; m < 2; ++m)
#pragma unroll
        for (int n = 0; n < 4; ++n)
#pragma unroll
            for (int r = 0; r < 4; ++r)
                S4[w][m * 16 + laneK * 4 + r][n * 16 + laneR] = sc[m][n][r];
    __syncthreads();

    // --- masked softmax: thread -> row q=t>>3, 8 cols starting (t&7)*8 ---
    {
        int q = t >> 3;
        int c0 = (t & 7) * 8;
        int lo = q + 1;
        if (32 - i0 > lo) lo = 32 - i0;  // only binds when i0 == 0
        int hi = q + 32;
        float vals[8];
        float mx = -1e30f;
#pragma unroll
        for (int c = 0; c < 8; ++c) {
            int cc = c0 + c;
            float v = (S4[0][q][cc] + S4[1][q][cc] + S4[2][q][cc] + S4[3][q][cc]) * 0.03125f;
            bool valid = (cc >= lo) && (cc <= hi);
            vals[c] = valid ? v : -1e30f;
            if (vals[c] > mx) mx = vals[c];
        }
#pragma unroll
        for (int d = 1; d < 8; d <<= 1) {
            float o = __shfl_xor(mx, d);
            if (o > mx) mx = o;
        }
        float sum = 0.f;
        float es[8];
#pragma unroll
        for (int c = 0; c < 8; ++c) {
            es[c] = (vals[c] > -1e29f) ? __expf(vals[c] - mx) : 0.f;
            sum += es[c];
        }
#pragma unroll
        for (int d = 1; d < 8; d <<= 1) sum += __shfl_xor(sum, d);
        float inv = 1.0f / sum;
#pragma unroll
        for (int c = 0; c < 8; ++c) P[q][c0 + c] = f2bf(es[c] * inv);
    }
    __syncthreads();

    // --- PV: wave w covers cols [w*256, w*256+256) in 4 chunks of 64 ---
    for (int nc = 0; nc < 4; ++nc) {
        int ncol = w * 256 + nc * 64;
        f32x4 o[2][4] = {};
#pragma unroll
        for (int ks = 0; ks < 2; ++ks) {
            bfx8 pa[2];
#pragma unroll
            for (int m = 0; m < 2; ++m)
                pa[m] = *(const bfx8*)(&P[m * 16 + laneR][ks * 32 + laneK * 8]);
#pragma unroll
            for (int n = 0; n < 4; ++n) {
                bfx8 vb;
                int col = ncol + n * 16 + laneR;
                int kb0 = ks * 32 + laneK * 8;
#pragma unroll
                for (int j = 0; j < 8; ++j) {
                    int krow = i0 - 32 + kb0 + j;
                    int kc = krow < 0 ? 0 : krow;
                    vb[j] = *(const __bf16*)(V + base + (size_t)kc * H + col);
                }
#pragma unroll
                for (int m = 0; m < 2; ++m)
                    o[m][n] = __builtin_amdgcn_mfma_f32_16x16x32_bf16(
                        pa[m], vb, o[m][n], 0, 0, 0);
            }
        }
#pragma unroll
        for (int m = 0; m < 2; ++m)
#pragma unroll
            for (int n = 0; n < 4; ++n)
#pragma unroll
                for (int r = 0; r < 4; ++r) {
                    size_t row = (size_t)(i0 + m * 16 + laneK * 4 + r);
                    O[base + row * H + ncol + n * 16 + laneR] = f2bf(o[m][n][r]);
                }
    }
}

// ---------------------------------------------------------------------------
// LayerNorm over H=1024, one block per row, f32 in -> bf16 out
// ---------------------------------------------------------------------------
__global__ __launch_bounds__(256)
void ln_kernel(const float* __restrict__ x, const float* __restrict__ gw,
               const float* __restrict__ gb, u16* __restrict__ out) {
    const int row = blockIdx.x, t = threadIdx.x;
    const float4 v = ((const float4*)(x + (size_t)row * 1024))[t];
    float s = v.x + v.y + v.z + v.w;
    float s2 = v.x * v.x + v.y * v.y + v.z * v.z + v.w * v.w;
#pragma unroll
    for (int d = 1; d < 64; d <<= 1) {
        s += __shfl_xor(s, d);
        s2 += __shfl_xor(s2, d);
    }
    __shared__ float red[8];
    int lane = t & 63, wv = t >> 6;
    if (lane == 0) { red[wv] = s; red[4 + wv] = s2; }
    __syncthreads();
    float S1 = red[0] + red[1] + red[2] + red[3];
    float S2 = red[4] + red[5] + red[6] + red[7];
    float mu = S1 * (1.0f / 1024.0f);
    float var = S2 * (1.0f / 1024.0f) - mu * mu;
    float rstd = rsqrtf(var + 1e-5f);
    const float4 wv4 = ((const float4*)gw)[t];
    const float4 bv4 = ((const float4*)gb)[t];
    ushort4 o;
    o.x = f2bf((v.x - mu) * rstd * wv4.x + bv4.x);
    o.y = f2bf((v.y - mu) * rstd * wv4.y + bv4.y);
    o.z = f2bf((v.z - mu) * rstd * wv4.z + bv4.z);
    o.w = f2bf((v.w - mu) * rstd * wv4.w + bv4.w);
    ((ushort4*)(out + (size_t)row * 1024))[t] = o;
}

// ---------------------------------------------------------------------------
extern "C" void kernel_launch(void* const* d_in, const int* in_sizes, int n_in,
                              void* d_out, int out_size, void* d_ws, size_t ws_size,
                              hipStream_t stream) {
    const float* x   = (const float*)d_in[0];
    const float* Wq  = (const float*)d_in[1];
    const float* Wk  = (const float*)d_in[2];
    const float* Wv  = (const float*)d_in[3];
    const float* Wo  = (const float*)d_in[4];
    const float* lnw = (const float*)d_in[5];
    const float* lnb = (const float*)d_in[6];
    const float* W1  = (const float*)d_in[7];
    const float* b1  = (const float*)d_in[8];
    const float* W2  = (const float*)d_in[9];
    const float* b2  = (const float*)d_in[10];
    (void)in_sizes; (void)n_in; (void)out_size; (void)ws_size; (void)lnb;

    const int M = 8192, H = 1024, Hh = 512;

    char* ws = (char*)d_ws;
    size_t off = 0;
    auto alloc = [&](size_t bytes) {
        char* p = ws + off;
        off += (bytes + 255) & ~(size_t)255;
        return p;
    };
    u16* Xb   = (u16*)alloc((size_t)M * H * 2);   // reused as Attb after QKV
    u16* Wqb  = (u16*)alloc((size_t)H * H * 2);
    u16* Wkb  = (u16*)alloc((size_t)H * H * 2);
    u16* Wvb  = (u16*)alloc((size_t)H * H * 2);
    u16* Wob  = (u16*)alloc((size_t)H * H * 2);
    u16* W1b  = (u16*)alloc((size_t)Hh * H * 2);
    u16* W2b  = (u16*)alloc((size_t)H * Hh * 2);
    u16* Qb   = (u16*)alloc((size_t)M * H * 2);   // reused as hlnb after attn
    u16* Kb   = (u16*)alloc((size_t)M * H * 2);   // reused as Gb after attn
    u16* Vb   = (u16*)alloc((size_t)M * H * 2);
    float* draft = (float*)alloc((size_t)M * H * 4);
    u16* Attb = Xb;
    u16* hlnb = Qb;
    u16* Gb   = Kb;
    float* outp = (float*)d_out;

    dim3 blk(256);
    auto cast = [&](const float* src, u16* dst, int n) {
        int n8 = n / 8;
        cast_bf16<<<dim3((n8 + 255) / 256), blk, 0, stream>>>(src, dst, n8);
    };
    cast(x, Xb, M * H);
    cast(Wq, Wqb, H * H);
    cast(Wk, Wkb, H * H);
    cast(Wv, Wvb, H * H);
    cast(Wo, Wob, H * H);
    cast(W1, W1b, Hh * H);
    cast(W2, W2b, H * Hh);

    gemm_nt<0><<<dim3(H / 128, M / 128), blk, 0, stream>>>(Xb, Wqb, Qb, nullptr, nullptr, nullptr, M, H, H);
    gemm_nt<0><<<dim3(H / 128, M / 128), blk, 0, stream>>>(Xb, Wkb, Kb, nullptr, nullptr, nullptr, M, H, H);
    gemm_nt<0><<<dim3(H / 128, M / 128), blk, 0, stream>>>(Xb, Wvb, Vb, nullptr, nullptr, nullptr, M, H, H);

    attn_kernel<<<dim3(256), blk, 0, stream>>>(Qb, Kb, Vb, Attb);

    gemm_nt<1><<<dim3(H / 128, M / 128), blk, 0, stream>>>(Attb, Wob, nullptr, draft, x, nullptr, M, H, H);

    ln_kernel<<<dim3(M), blk, 0, stream>>>(draft, lnw, lnb, hlnb);

    gemm_nt<2><<<dim3(Hh / 128, M / 128), blk, 0, stream>>>(hlnb, W1b, Gb, nullptr, nullptr, b1, M, Hh, H);
    gemm_nt<3><<<dim3(H / 128, M / 128), blk, 0, stream>>>(Gb, W2b, nullptr, outp, draft, b2, M, H, Hh);
}

// Round 2
// 190.620 us; speedup vs baseline: 1.0753x; 1.0753x over previous
//
#include <hip/hip_runtime.h>
#include <stdint.h>

typedef unsigned short u16;
typedef __bf16 bfx8 __attribute__((ext_vector_type(8)));
typedef float f32x4 __attribute__((ext_vector_type(4)));

__device__ __forceinline__ u16 f2bf(float x) {
    unsigned int u = __float_as_uint(x);
    u += 0x7fffu + ((u >> 16) & 1u);
    return (u16)(u >> 16);
}

__device__ __forceinline__ void async16(const void* g, void* l) {
    __builtin_amdgcn_global_load_lds(
        (const __attribute__((address_space(1))) unsigned int*)(uintptr_t)g,
        (__attribute__((address_space(3))) unsigned int*)(unsigned int)(uintptr_t)l,
        16, 0, 0);
}

#define S_BARRIER() asm volatile("s_barrier" ::: "memory")
#define WAIT_VM(n) asm volatile("s_waitcnt vmcnt(" #n ")" ::: "memory")

// ---------------------------------------------------------------------------
// fused cast: 7 segments of f32 -> bf16, 8 elems/thread, one launch
// ---------------------------------------------------------------------------
struct CastArgs {
    const float* src[7];
    u16* dst[7];
    int nblk[7];
};
__global__ __launch_bounds__(256) void cast_all(CastArgs a) {
    int b = blockIdx.x, seg = 0;
    while (b >= a.nblk[seg]) { b -= a.nblk[seg]; ++seg; }
    int i = b * 256 + threadIdx.x;
    const float4* p = (const float4*)(a.src[seg] + (size_t)i * 8);
    float4 x = p[0], y = p[1];
    ushort4 o0, o1;
    o0.x = f2bf(x.x); o0.y = f2bf(x.y); o0.z = f2bf(x.z); o0.w = f2bf(x.w);
    o1.x = f2bf(y.x); o1.y = f2bf(y.y); o1.z = f2bf(y.z); o1.w = f2bf(y.w);
    ushort4* q = (ushort4*)(a.dst[seg] + (size_t)i * 8);
    q[0] = o0; q[1] = o1;
}

// ---------------------------------------------------------------------------
// NT GEMM: C[M,N] = A[M,K] * Bw[N,K]^T  (bf16 in, f32 acc)
// BM=256, BN=128, BK=64, 512 threads = 8 waves (4M x 2N), wave tile 64x64.
// 3-deep LDS ring, depth-2 prefetch, counted vmcnt(6), raw s_barrier,
// 2 compute phases per K-tile, setprio around MFMA cluster.
// LDS XOR swizzle: 16B chunk ko stored at slot ko ^ (row&7) (both sides).
// EPI 0: QKV split epilogue -> outq rows, outk rows, vt = V transposed
// EPI 1: outf = res + C
// EPI 2: outb = bf16(gelu(C + bias))
// EPI 3: outf = res + C + bias
// ---------------------------------------------------------------------------
template <int EPI>
__global__ __launch_bounds__(512, 2)
void gemm_nt(const u16* __restrict__ A, const u16* __restrict__ Bw,
             u16* __restrict__ outb, float* __restrict__ outf,
             const float* __restrict__ res, const float* __restrict__ bias,
             u16* __restrict__ outq, u16* __restrict__ outk,
             u16* __restrict__ vt, int M, int N, int K) {
    __shared__ __align__(1024) unsigned char lds[147456];  // 3 * (32K A + 16K B)
    const int t = threadIdx.x;
    const int lane = t & 63, w = t >> 6;
    const int laneR = lane & 15, laneK = lane >> 4;
    const int wr = w >> 1, wc = w & 1;
    const int row0 = blockIdx.y * 256, col0 = blockIdx.x * 128;
    const int nt = K >> 6;

    f32x4 acc[4][4] = {};

    const u16* srcA[4];
    const u16* srcB[2];
    unsigned dA[4], dB[2];
#pragma unroll
    for (int i = 0; i < 4; ++i) {
        int li = i * 512 + t;                 // A: 2048 16B-chunks (256 rows x 8)
        int row = li >> 3, ko = li & 7;
        srcA[i] = A + (size_t)(row0 + row) * K + (ko ^ (row & 7)) * 8;
        dA[i] = li * 16;
    }
#pragma unroll
    for (int i = 0; i < 2; ++i) {
        int li = i * 512 + t;                 // B: 1024 chunks (128 rows x 8)
        int row = li >> 3, ko = li & 7;
        srcB[i] = Bw + (size_t)(col0 + row) * K + (ko ^ (row & 7)) * 8;
        dB[i] = 32768 + li * 16;
    }

    auto stage = [&](int b, int tk, int h) {
        unsigned char* base = lds + b * 49152;
        const int o = tk * 64;                // +64 bf16 per K-tile
        if (h == 0) {
            async16(srcA[0] + o, base + dA[0]);
            async16(srcA[1] + o, base + dA[1]);
            async16(srcB[0] + o, base + dB[0]);
        } else {
            async16(srcA[2] + o, base + dA[2]);
            async16(srcA[3] + o, base + dA[3]);
            async16(srcB[1] + o, base + dB[1]);
        }
    };

    // prologue: 2 tiles in flight (12 loads/thread out)
    stage(0, 0, 0); stage(0, 0, 1);
    stage(1, 1, 0); stage(1, 1, 1);

    for (int tk = 0; tk < nt; ++tk) {
        unsigned char* bufA = lds + (tk % 3) * 49152;
        unsigned char* bufB = bufA + 32768;
        if (tk + 1 < nt) { WAIT_VM(6); } else { WAIT_VM(0); }
        S_BARRIER();                           // all waves' portions of tile tk landed
        const bool pf = (tk + 2 < nt);
        const int nb = (tk + 2) % 3;
#pragma unroll
        for (int ks = 0; ks < 2; ++ks) {
            bfx8 af[4], bf[4];
#pragma unroll
            for (int m = 0; m < 4; ++m) {
                int r = wr * 64 + m * 16 + laneR;
                int phys = (ks * 4 + laneK) ^ (r & 7);
                af[m] = *(const bfx8*)(bufA + r * 128 + phys * 16);
            }
#pragma unroll
            for (int n = 0; n < 4; ++n) {
                int r = wc * 64 + n * 16 + laneR;
                int phys = (ks * 4 + laneK) ^ (r & 7);
                bf[n] = *(const bfx8*)(bufB + r * 128 + phys * 16);
            }
            if (pf) stage(nb, tk + 2, ks);     // prefetch into idle ring slot
            S_BARRIER();
            __builtin_amdgcn_s_setprio(1);
#pragma unroll
            for (int m = 0; m < 4; ++m)
#pragma unroll
                for (int n = 0; n < 4; ++n)
                    acc[m][n] = __builtin_amdgcn_mfma_f32_16x16x32_bf16(
                        af[m], bf[n], acc[m][n], 0, 0, 0);
            __builtin_amdgcn_s_setprio(0);
            S_BARRIER();
        }
    }

    // epilogue: D reg r of lane l -> row laneK*4+r, col laneR per 16x16 frag
#pragma unroll
    for (int m = 0; m < 4; ++m) {
        const int gr0 = row0 + wr * 64 + m * 16 + laneK * 4;
#pragma unroll
        for (int n = 0; n < 4; ++n) {
            const int gc = col0 + wc * 64 + n * 16 + laneR;
            if constexpr (EPI == 0) {
                if (col0 < 1024) {
#pragma unroll
                    for (int r = 0; r < 4; ++r)
                        outq[(size_t)(gr0 + r) * 1024 + gc] = f2bf(acc[m][n][r]);
                } else if (col0 < 2048) {
#pragma unroll
                    for (int r = 0; r < 4; ++r)
                        outk[(size_t)(gr0 + r) * 1024 + (gc - 1024)] = f2bf(acc[m][n][r]);
                } else {
                    // V transposed: vt[batch][col][row], batch = gr>>12
                    ushort4 o4;
                    o4.x = f2bf(acc[m][n][0]); o4.y = f2bf(acc[m][n][1]);
                    o4.z = f2bf(acc[m][n][2]); o4.w = f2bf(acc[m][n][3]);
                    *(ushort4*)(vt + (((size_t)(gr0 >> 12)) * 1024 + (gc - 2048)) * 4096 +
                                (gr0 & 4095)) = o4;
                }
            } else if constexpr (EPI == 1) {
#pragma unroll
                for (int r = 0; r < 4; ++r) {
                    size_t idx = (size_t)(gr0 + r) * N + gc;
                    outf[idx] = res[idx] + acc[m][n][r];
                }
            } else if constexpr (EPI == 2) {
#pragma unroll
                for (int r = 0; r < 4; ++r) {
                    float xx = acc[m][n][r] + bias[gc];
                    outb[(size_t)(gr0 + r) * N + gc] =
                        f2bf(xx * 0.5f * (1.0f + erff(xx * 0.70710678118654752f)));
                }
            } else {
#pragma unroll
                for (int r = 0; r < 4; ++r) {
                    size_t idx = (size_t)(gr0 + r) * N + gc;
                    outf[idx] = res[idx] + acc[m][n][r] + bias[gc];
                }
            }
        }
    }
}

// ---------------------------------------------------------------------------
// banded attention: WINDOW=32, 32-query tiles, 64-key band [i0-32, i0+31]
// QK^T via MFMA (4 waves x 256-H-chunk partials -> LDS reduce), masked
// wave-parallel softmax, PV via MFMA with B-frags as contiguous bfx8 from V^T.
// ---------------------------------------------------------------------------
__global__ __launch_bounds__(256, 2)
void attn_kernel(const u16* __restrict__ Q, const u16* __restrict__ K,
                 const u16* __restrict__ vt, u16* __restrict__ O) {
    constexpr int H = 1024, S = 4096;
    const int t = threadIdx.x, lane = t & 63, w = t >> 6;
    const int laneR = lane & 15, laneK = lane >> 4;
    const int tile = blockIdx.x;      // 0..255
    const int batch = tile >> 7;
    const int i0 = (tile & 127) * 32;
    const size_t base = (size_t)batch * S * H;

    __shared__ __align__(16) float S4[4][32][64];
    __shared__ __align__(16) u16 P[32][72];

    // --- QK^T: wave w handles H-chunk [w*256, w*256+256) ---
    f32x4 sc[2][4] = {};
    for (int h = w * 256; h < w * 256 + 256; h += 32) {
        bfx8 qa[2];
#pragma unroll
        for (int m = 0; m < 2; ++m) {
            size_t row = (size_t)(i0 + m * 16 + laneR);
            qa[m] = *(const bfx8*)(Q + base + row * H + h + laneK * 8);
        }
        bfx8 kb[4];
#pragma unroll
        for (int n = 0; n < 4; ++n) {
            int j = i0 - 32 + n * 16 + laneR;
            int jc = j < 0 ? 0 : j;
            kb[n] = *(const bfx8*)(K + base + (size_t)jc * H + h + laneK * 8);
        }
#pragma unroll
        for (int m = 0; m < 2; ++m)
#pragma unroll
            for (int n = 0; n < 4; ++n)
                sc[m][n] = __builtin_amdgcn_mfma_f32_16x16x32_bf16(
                    qa[m], kb[n], sc[m][n], 0, 0, 0);
    }
#pragma unroll
    for (int m = 0; m < 2; ++m)
#pragma unroll
        for (int n = 0; n < 4; ++n)
#pragma unroll
            for (int r = 0; r < 4; ++r)
                S4[w][m * 16 + laneK * 4 + r][n * 16 + laneR] = sc[m][n][r];
    __syncthreads();

    // --- masked softmax: thread -> row q=t>>3, 8 cols starting (t&7)*8 ---
    {
        int q = t >> 3;
        int c0 = (t & 7) * 8;
        int lo = q + 1;
        if (32 - i0 > lo) lo = 32 - i0;
        int hi = q + 32;
        float vals[8];
        float mx = -1e30f;
#pragma unroll
        for (int c = 0; c < 8; ++c) {
            int cc = c0 + c;
            float v = (S4[0][q][cc] + S4[1][q][cc] + S4[2][q][cc] + S4[3][q][cc]) * 0.03125f;
            bool valid = (cc >= lo) && (cc <= hi);
            vals[c] = valid ? v : -1e30f;
            if (vals[c] > mx) mx = vals[c];
        }
#pragma unroll
        for (int d = 1; d < 8; d <<= 1) {
            float o = __shfl_xor(mx, d);
            if (o > mx) mx = o;
        }
        float sum = 0.f;
        float es[8];
#pragma unroll
        for (int c = 0; c < 8; ++c) {
            es[c] = (vals[c] > -1e29f) ? __expf(vals[c] - mx) : 0.f;
            sum += es[c];
        }
#pragma unroll
        for (int d = 1; d < 8; d <<= 1) sum += __shfl_xor(sum, d);
        float inv = 1.0f / sum;
#pragma unroll
        for (int c = 0; c < 8; ++c) P[q][c0 + c] = f2bf(es[c] * inv);
    }
    __syncthreads();

    // --- PV: wave w covers H-cols [w*256, w*256+256), B-frags from V^T ---
    for (int nc = 0; nc < 4; ++nc) {
        int ncol = w * 256 + nc * 64;
        f32x4 o[2][4] = {};
#pragma unroll
        for (int ks = 0; ks < 2; ++ks) {
            bfx8 pa[2];
#pragma unroll
            for (int m = 0; m < 2; ++m)
                pa[m] = *(const bfx8*)(&P[m * 16 + laneR][ks * 32 + laneK * 8]);
            int t0 = i0 - 32 + ks * 32 + laneK * 8;
            if (t0 < 0) t0 = 0;   // whole chunk masked (P=0) when i0==0, ks==0
#pragma unroll
            for (int n = 0; n < 4; ++n) {
                int c = ncol + n * 16 + laneR;
                bfx8 vb = *(const bfx8*)(vt + ((size_t)batch * 1024 + c) * 4096 + t0);
#pragma unroll
                for (int m = 0; m < 2; ++m)
                    o[m][n] = __builtin_amdgcn_mfma_f32_16x16x32_bf16(
                        pa[m], vb, o[m][n], 0, 0, 0);
            }
        }
#pragma unroll
        for (int m = 0; m < 2; ++m)
#pragma unroll
            for (int n = 0; n < 4; ++n)
#pragma unroll
                for (int r = 0; r < 4; ++r) {
                    size_t row = (size_t)(i0 + m * 16 + laneK * 4 + r);
                    O[base + row * H + ncol + n * 16 + laneR] = f2bf(o[m][n][r]);
                }
    }
}

// ---------------------------------------------------------------------------
// LayerNorm over H=1024, one block per row, f32 in -> bf16 out
// ---------------------------------------------------------------------------
__global__ __launch_bounds__(256)
void ln_kernel(const float* __restrict__ x, const float* __restrict__ gw,
               const float* __restrict__ gb, u16* __restrict__ out) {
    const int row = blockIdx.x, t = threadIdx.x;
    const float4 v = ((const float4*)(x + (size_t)row * 1024))[t];
    float s = v.x + v.y + v.z + v.w;
    float s2 = v.x * v.x + v.y * v.y + v.z * v.z + v.w * v.w;
#pragma unroll
    for (int d = 1; d < 64; d <<= 1) {
        s += __shfl_xor(s, d);
        s2 += __shfl_xor(s2, d);
    }
    __shared__ float red[8];
    int lane = t & 63, wv = t >> 6;
    if (lane == 0) { red[wv] = s; red[4 + wv] = s2; }
    __syncthreads();
    float S1 = red[0] + red[1] + red[2] + red[3];
    float S2 = red[4] + red[5] + red[6] + red[7];
    float mu = S1 * (1.0f / 1024.0f);
    float var = S2 * (1.0f / 1024.0f) - mu * mu;
    float rstd = rsqrtf(var + 1e-5f);
    const float4 wv4 = ((const float4*)gw)[t];
    const float4 bv4 = ((const float4*)gb)[t];
    ushort4 o;
    o.x = f2bf((v.x - mu) * rstd * wv4.x + bv4.x);
    o.y = f2bf((v.y - mu) * rstd * wv4.y + bv4.y);
    o.z = f2bf((v.z - mu) * rstd * wv4.z + bv4.z);
    o.w = f2bf((v.w - mu) * rstd * wv4.w + bv4.w);
    ((ushort4*)(out + (size_t)row * 1024))[t] = o;
}

// ---------------------------------------------------------------------------
extern "C" void kernel_launch(void* const* d_in, const int* in_sizes, int n_in,
                              void* d_out, int out_size, void* d_ws, size_t ws_size,
                              hipStream_t stream) {
    const float* x   = (const float*)d_in[0];
    const float* Wq  = (const float*)d_in[1];
    const float* Wk  = (const float*)d_in[2];
    const float* Wv  = (const float*)d_in[3];
    const float* Wo  = (const float*)d_in[4];
    const float* lnw = (const float*)d_in[5];
    const float* lnb = (const float*)d_in[6];
    const float* W1  = (const float*)d_in[7];
    const float* b1  = (const float*)d_in[8];
    const float* W2  = (const float*)d_in[9];
    const float* b2  = (const float*)d_in[10];
    (void)in_sizes; (void)n_in; (void)out_size; (void)ws_size;

    const int M = 8192, H = 1024, Hh = 512;

    char* ws = (char*)d_ws;
    size_t off = 0;
    auto alloc = [&](size_t bytes) {
        char* p = ws + off;
        off += (bytes + 255) & ~(size_t)255;
        return p;
    };
    u16* Xb    = (u16*)alloc((size_t)M * H * 2);      // reused as Attb after QKV
    u16* Wqkvb = (u16*)alloc((size_t)3 * H * H * 2);  // [3072][1024]
    u16* Wob   = (u16*)alloc((size_t)H * H * 2);
    u16* W1b   = (u16*)alloc((size_t)Hh * H * 2);
    u16* W2b   = (u16*)alloc((size_t)H * Hh * 2);
    u16* Qb    = (u16*)alloc((size_t)M * H * 2);      // reused as hlnb after attn
    u16* Kb    = (u16*)alloc((size_t)M * H * 2);      // reused as Gb after attn
    u16* Vt    = (u16*)alloc((size_t)M * H * 2);      // [2][1024][4096] V^T
    float* draft = (float*)alloc((size_t)M * H * 4);
    u16* Attb = Xb;
    u16* hlnb = Qb;
    u16* Gb   = Kb;
    float* outp = (float*)d_out;

    // one fused cast launch (all segments block-aligned: n8 % 256 == 0)
    CastArgs ca;
    ca.src[0] = x;  ca.dst[0] = Xb;                   ca.nblk[0] = (M * H / 8) / 256;
    ca.src[1] = Wq; ca.dst[1] = Wqkvb;                ca.nblk[1] = (H * H / 8) / 256;
    ca.src[2] = Wk; ca.dst[2] = Wqkvb + (size_t)H * H;     ca.nblk[2] = (H * H / 8) / 256;
    ca.src[3] = Wv; ca.dst[3] = Wqkvb + (size_t)2 * H * H; ca.nblk[3] = (H * H / 8) / 256;
    ca.src[4] = Wo; ca.dst[4] = Wob;                  ca.nblk[4] = (H * H / 8) / 256;
    ca.src[5] = W1; ca.dst[5] = W1b;                  ca.nblk[5] = (Hh * H / 8) / 256;
    ca.src[6] = W2; ca.dst[6] = W2b;                  ca.nblk[6] = (H * Hh / 8) / 256;
    int totblk = 0;
    for (int i = 0; i < 7; ++i) totblk += ca.nblk[i];
    cast_all<<<dim3(totblk), dim3(256), 0, stream>>>(ca);

    dim3 gblk(512);
    // fused QKV GEMM: N=3072, V columns stored transposed
    gemm_nt<0><<<dim3(3 * H / 128, M / 256), gblk, 0, stream>>>(
        Xb, Wqkvb, nullptr, nullptr, nullptr, nullptr, Qb, Kb, Vt, M, 3 * H, H);

    attn_kernel<<<dim3(256), dim3(256), 0, stream>>>(Qb, Kb, Vt, Attb);

    gemm_nt<1><<<dim3(H / 128, M / 256), gblk, 0, stream>>>(
        Attb, Wob, nullptr, draft, x, nullptr, nullptr, nullptr, nullptr, M, H, H);

    ln_kernel<<<dim3(M), dim3(256), 0, stream>>>(draft, lnw, lnb, hlnb);

    gemm_nt<2><<<dim3(Hh / 128, M / 256), gblk, 0, stream>>>(
        hlnb, W1b, Gb, nullptr, nullptr, b1, nullptr, nullptr, nullptr, M, Hh, H);

    gemm_nt<3><<<dim3(H / 128, M / 256), gblk, 0, stream>>>(
        Gb, W2b, nullptr, outp, draft, b2, nullptr, nullptr, nullptr, M, H, Hh);
}